// Round 1
// 262.012 us; speedup vs baseline: 1.1008x; 1.1008x over previous
//
#include <hip/hip_runtime.h>
#include <hip/hip_fp16.h>
#include <math.h>
#include <stdint.h>

#define HH 512
#define WW 512
#define NIMG 24
#define CCH 3
#define TAU 0.25f
#define TVEPS 2e-4f
#define NUMEL 262144.0f
#define NITER 10

// ws layout (ws_size = 256 MiB):
//   byte 0        : sc — 2 slots x 96 floats, slot s at sc+96*s:
//                   [0..23]=E_prev, [24..47]=E_init, int[48..71]=done, int[72..95]=last_k
//                   slot (it&1) holds state S_{it-1} after kernel `it` runs.
//   byte 4096     : pd [2][NIMG][64]  (slot = it&1)
//   byte 16384    : pn [2][NIMG][64]
//   byte 32768    : imgh (__half, 24*512*512)
//   byte 12615680 : ptA (uint32 packed half2)
//   byte 37781504 : ptB

__device__ __forceinline__ float2 h2f(uint32_t v) {
    __half2 h; *reinterpret_cast<uint32_t*>(&h) = v;
    return __half22float2(h);
}
__device__ __forceinline__ uint32_t f2h2(float a, float b) {
    __half2 h = __floats2half2_rn(a, b);
    return *reinterpret_cast<uint32_t*>(&h);
}
__device__ __forceinline__ void h4_to_f(uint2 hv, float* f) {
    float2 a = h2f(hv.x), b = h2f(hv.y);
    f[0] = a.x; f[1] = a.y; f[2] = b.x; f[3] = b.y;
}

__device__ __forceinline__ void block_reduce_store(float v0, float v1,
                                                   float* p0, float* p1, int tid) {
    for (int off = 32; off > 0; off >>= 1) {
        v0 += __shfl_down(v0, off, 64);
        v1 += __shfl_down(v1, off, 64);
    }
    __shared__ float sr[2][4];
    int wave = tid >> 6, lane = tid & 63;
    if (lane == 0) { sr[0][wave] = v0; sr[1][wave] = v1; }
    __syncthreads();
    if (tid == 0) {
        *p0 = (sr[0][0] + sr[0][1]) + (sr[0][2] + sr[0][3]);
        *p1 = (sr[1][0] + sr[1][1]) + (sr[1][2] + sr[1][3]);
    }
}

__device__ __forceinline__ void block_reduce_store1(float v, float* p, int tid) {
    for (int off = 32; off > 0; off >>= 1) v += __shfl_down(v, off, 64);
    __shared__ float sr[4];
    if ((tid & 63) == 0) sr[tid >> 6] = v;
    __syncthreads();
    if (tid == 0) *p = (sr[0] + sr[1]) + (sr[2] + sr[3]);
}

// Iteration 0: out = img. 4px-wide strips, all global I/O 16B.
__global__ __launch_bounds__(256, 4) void tv_step0(
    const float* __restrict__ img, const float* __restrict__ weight,
    __half* __restrict__ imgh, uint32_t* __restrict__ ptout,
    float* __restrict__ pn)
{
    const int im = blockIdx.z;
    const int bid = blockIdx.y * 8 + blockIdx.x;
    const float w = weight[im / CCH];
    const int x0 = blockIdx.x * 64, y0 = blockIdx.y * 64;
    const float* imgI = img + (size_t)im * HH * WW;
    __half* hI = imgh + (size_t)im * HH * WW;
    uint32_t* pI = ptout + (size_t)im * HH * WW;
    __shared__ float s[65][68];
    const int tid = threadIdx.x;
    const int tx = tid & 15, ry = tid >> 4;
    const int gx = x0 + 4 * tx;

    float o[4][4];
    #pragma unroll
    for (int i = 0; i < 4; ++i) {
        int ey = ry + 16 * i, gy = y0 + ey;
        float4 v = *(const float4*)(imgI + (size_t)gy * WW + gx);
        o[i][0] = v.x; o[i][1] = v.y; o[i][2] = v.z; o[i][3] = v.w;
        *(float4*)&s[ey][4 * tx] = v;
    }
    if (tx == 15 && x0 + 64 < WW) {
        #pragma unroll
        for (int i = 0; i < 4; ++i) {
            int ey = ry + 16 * i, gy = y0 + ey;
            s[ey][64] = imgI[(size_t)gy * WW + x0 + 64];
        }
    }
    if (ry == 0 && y0 + 64 < HH) {
        *(float4*)&s[64][4 * tx] = *(const float4*)(imgI + (size_t)(y0 + 64) * WW + gx);
    }
    __syncthreads();

    float accn = 0.f;
    const float tw = TAU / w;
    #pragma unroll
    for (int i = 0; i < 4; ++i) {
        int ey = ry + 16 * i, gy = y0 + ey;
        float4 dn = *(float4*)&s[ey + 1][4 * tx];
        float rt_sh = __shfl_down(o[i][0], 1, 64);
        float rt = (tx == 15) ? s[ey][64] : rt_sh;
        float dnv[4] = {dn.x, dn.y, dn.z, dn.w};
        uint32_t pv[4];
        #pragma unroll
        for (int j = 0; j < 4; ++j) {
            float ov = o[i][j];
            float g0 = (gy < HH - 1) ? dnv[j] - ov : 0.f;
            float rn = (j < 3) ? o[i][j + 1] : rt;
            float g1 = (gx + j < WW - 1) ? rn - ov : 0.f;
            float ss2 = g0 * g0 + g1 * g1;
            float nrm = (ss2 > 0.f) ? sqrtf(ss2) : 0.f;
            accn += nrm;
            float inv = __builtin_amdgcn_rcpf(1.f + tw * nrm);
            pv[j] = f2h2(-TAU * g0 * inv, -TAU * g1 * inv);
        }
        size_t off = (size_t)gy * WW + gx;
        *(uint4*)(pI + off) = make_uint4(pv[0], pv[1], pv[2], pv[3]);
        *(uint2*)(hI + off) = make_uint2(f2h2(o[i][0], o[i][1]), f2h2(o[i][2], o[i][3]));
    }
    // partials slot 0 (consumed by it=1's replay)
    block_reduce_store1(accn, &pn[im * 64 + bid], tid);
}

// Iterations 1..8. Head replays previous step's partials to derive convergence
// state S_{it-1} (identical FP order in every block -> identical decision).
__global__ __launch_bounds__(256, 4) void tv_stepN(
    int it,
    const __half* __restrict__ imgh, const float* __restrict__ weight,
    const uint32_t* __restrict__ pt_in, uint32_t* __restrict__ pt_out,
    float* __restrict__ sc, float* __restrict__ pd, float* __restrict__ pn)
{
    const int im = blockIdx.z;
    const int bid = blockIdx.y * 8 + blockIdx.x;
    const int tid = threadIdx.x;
    const float w = weight[im / CCH];

    __shared__ int sh_done;
    {
        const int slot = (it - 1) & 1;
        if (tid < 64) {
            float d = 0.f, n = pn[(slot * NIMG + im) * 64 + tid];
            if (it > 1) d = pd[(slot * NIMG + im) * 64 + tid];
            for (int off = 32; off > 0; off >>= 1) {
                d += __shfl_down(d, off, 64);
                n += __shfl_down(n, off, 64);
            }
            if (tid == 0) {
                float Eprev, Einit; int done, lastk;
                if (it == 1) {
                    float E0 = w * n / NUMEL;
                    Eprev = E0; Einit = E0; done = 0; lastk = 0;
                } else {
                    const float* sIn = sc + slot * 96;
                    Eprev = sIn[im]; Einit = sIn[24 + im];
                    done = ((const int*)sIn)[48 + im];
                    lastk = ((const int*)sIn)[72 + im];
                    if (!done) {
                        float Et = (d + w * n) / NUMEL;
                        if (fabsf(Eprev - Et) < TVEPS * Einit) { done = 1; lastk = it - 1; }
                        Eprev = Et;
                    }
                }
                if (bid == 0) {  // persist S_{it-1} for kernel it+1 / tv_out
                    float* sOut = sc + (it & 1) * 96;
                    sOut[im] = Eprev; sOut[24 + im] = Einit;
                    ((int*)sOut)[48 + im] = done;
                    ((int*)sOut)[72 + im] = lastk;
                }
                sh_done = done;
            }
        }
    }
    __syncthreads();
    if (sh_done) return;  // frozen image

    const int x0 = blockIdx.x * 64, y0 = blockIdx.y * 64;
    const __half* hI = imgh + (size_t)im * HH * WW;
    const uint32_t* pinI = pt_in + (size_t)im * HH * WW;
    uint32_t* poutI = pt_out + (size_t)im * HH * WW;
    __shared__ float s[65][68];
    const int tx = tid & 15, ry = tid >> 4;
    const int gx = x0 + 4 * tx;

    uint32_t c[4][4];
    float o[4][4], im4[4][4];

    #pragma unroll
    for (int i = 0; i < 4; ++i) {
        int ey = ry + 16 * i, gy = y0 + ey;
        size_t off = (size_t)gy * WW + gx;
        uint4 cv = *(const uint4*)(pinI + off);
        uint4 uv = make_uint4(0u, 0u, 0u, 0u);
        if (gy > 0) uv = *(const uint4*)(pinI + off - WW);
        uint32_t lf = (gx > 0) ? pinI[off - 1] : 0u;
        uint2 hv = *(const uint2*)(hI + off);
        float imv[4]; h4_to_f(hv, imv);
        c[i][0] = cv.x; c[i][1] = cv.y; c[i][2] = cv.z; c[i][3] = cv.w;
        uint32_t uu[4] = {uv.x, uv.y, uv.z, uv.w};
        uint32_t lt[4] = {lf, cv.x, cv.y, cv.z};
        #pragma unroll
        for (int j = 0; j < 4; ++j) {
            float2 cf = h2f(c[i][j]);
            float dt = -(cf.x + cf.y) + h2f(uu[j]).x + h2f(lt[j]).y;
            o[i][j] = imv[j] + dt;
            im4[i][j] = imv[j];
        }
        *(float4*)&s[ey][4 * tx] = make_float4(o[i][0], o[i][1], o[i][2], o[i][3]);
    }
    if (tx == 15 && x0 + 64 < WW) {
        #pragma unroll
        for (int i = 0; i < 4; ++i) {
            int ey = ry + 16 * i, gy = y0 + ey;
            size_t off = (size_t)gy * WW + x0 + 64;
            uint32_t c2 = pinI[off];
            uint32_t u2 = (gy > 0) ? pinI[off - WW] : 0u;
            float2 cf = h2f(c2);
            float dt = -(cf.x + cf.y) + h2f(u2).x + h2f(c[i][3]).y;
            s[ey][64] = __half2float(hI[off]) + dt;
        }
    }
    if (ry == 0 && y0 + 64 < HH) {
        int gy = y0 + 64;
        size_t off = (size_t)gy * WW + gx;
        uint4 cv = *(const uint4*)(pinI + off);
        uint4 uv = *(const uint4*)(pinI + off - WW);
        uint32_t lf = (gx > 0) ? pinI[off - 1] : 0u;
        uint2 hv = *(const uint2*)(hI + off);
        float imv[4]; h4_to_f(hv, imv);
        uint32_t cc[4] = {cv.x, cv.y, cv.z, cv.w};
        uint32_t uu[4] = {uv.x, uv.y, uv.z, uv.w};
        uint32_t lt[4] = {lf, cv.x, cv.y, cv.z};
        float ob[4];
        #pragma unroll
        for (int j = 0; j < 4; ++j) {
            float2 cf = h2f(cc[j]);
            ob[j] = imv[j] + (-(cf.x + cf.y) + h2f(uu[j]).x + h2f(lt[j]).y);
        }
        *(float4*)&s[64][4 * tx] = make_float4(ob[0], ob[1], ob[2], ob[3]);
    }
    __syncthreads();

    float accd = 0.f, accn = 0.f;
    const float tw = TAU / w;
    #pragma unroll
    for (int i = 0; i < 4; ++i) {
        int ey = ry + 16 * i, gy = y0 + ey;
        float4 dn = *(float4*)&s[ey + 1][4 * tx];
        float rt_sh = __shfl_down(o[i][0], 1, 64);
        float rt = (tx == 15) ? s[ey][64] : rt_sh;
        float dnv[4] = {dn.x, dn.y, dn.z, dn.w};
        uint32_t pv[4];
        #pragma unroll
        for (int j = 0; j < 4; ++j) {
            float ov = o[i][j];
            float g0 = (gy < HH - 1) ? dnv[j] - ov : 0.f;
            float rn = (j < 3) ? o[i][j + 1] : rt;
            float g1 = (gx + j < WW - 1) ? rn - ov : 0.f;
            float ss2 = g0 * g0 + g1 * g1;
            float nrm = (ss2 > 0.f) ? sqrtf(ss2) : 0.f;
            accn += nrm;
            float dt = ov - im4[i][j];
            accd += dt * dt;
            float inv = __builtin_amdgcn_rcpf(1.f + tw * nrm);
            float2 cf = h2f(c[i][j]);
            pv[j] = f2h2((cf.x - TAU * g0) * inv, (cf.y - TAU * g1) * inv);
        }
        *(uint4*)(poutI + (size_t)gy * WW + gx) = make_uint4(pv[0], pv[1], pv[2], pv[3]);
    }
    block_reduce_store(accd, accn,
                       &pd[((it & 1) * NIMG + im) * 64 + bid],
                       &pn[((it & 1) * NIMG + im) * 64 + bid], tid);
}

// Epilogue: out = img(fp32) + div(pt input of each image's last executed step).
// Head replays it=8's partials against S_7 (sc slot 0) to get final state S_8.
__global__ __launch_bounds__(256, 4) void tv_out(
    const float* __restrict__ img, float* __restrict__ out,
    const uint32_t* __restrict__ ptA, const uint32_t* __restrict__ ptB,
    const float* __restrict__ weight, const float* __restrict__ sc,
    const float* __restrict__ pd, const float* __restrict__ pn)
{
    const int im = blockIdx.z;
    const int tid = threadIdx.x;
    const float w = weight[im / CCH];
    __shared__ int2 shk;
    if (tid < 64) {
        const float* sIn = sc;  // slot (8&1)=0 holds S_7
        int done = ((const int*)sIn)[48 + im];
        int lastk = ((const int*)sIn)[72 + im];
        if (!done) {
            float d = pd[im * 64 + tid];       // slot 0 = it 8's partials
            float n = pn[im * 64 + tid];
            for (int off = 32; off > 0; off >>= 1) {
                d += __shfl_down(d, off, 64);
                n += __shfl_down(n, off, 64);
            }
            if (tid == 0) {
                float Et = (d + w * n) / NUMEL;
                if (fabsf(sIn[im] - Et) < TVEPS * sIn[24 + im]) { done = 1; lastk = 8; }
            }
        }
        if (tid == 0) { shk.x = done; shk.y = lastk; }
    }
    __syncthreads();
    int k = shk.x ? shk.y : (NITER - 1);
    const uint32_t* p = ((((k - 1) & 1) == 0) ? ptA : ptB) + (size_t)im * HH * WW;
    const float* imgI = img + (size_t)im * HH * WW;
    float* outI = out + (size_t)im * HH * WW;
    const int x0 = blockIdx.x * 64, y0 = blockIdx.y * 64;
    const int tx = tid & 15, ry = tid >> 4;
    const int gx = x0 + 4 * tx;
    #pragma unroll
    for (int i = 0; i < 4; ++i) {
        int gy = y0 + ry + 16 * i;
        size_t off = (size_t)gy * WW + gx;
        uint4 cv = *(const uint4*)(p + off);
        uint4 uv = make_uint4(0u, 0u, 0u, 0u);
        if (gy > 0) uv = *(const uint4*)(p + off - WW);
        uint32_t lf = (gx > 0) ? p[off - 1] : 0u;
        float4 iv = *(const float4*)(imgI + off);
        uint32_t cc[4] = {cv.x, cv.y, cv.z, cv.w};
        uint32_t uu[4] = {uv.x, uv.y, uv.z, uv.w};
        uint32_t lt[4] = {lf, cv.x, cv.y, cv.z};
        float ivv[4] = {iv.x, iv.y, iv.z, iv.w};
        float r[4];
        #pragma unroll
        for (int j = 0; j < 4; ++j) {
            float2 cf = h2f(cc[j]);
            r[j] = ivv[j] + (-(cf.x + cf.y) + h2f(uu[j]).x + h2f(lt[j]).y);
        }
        *(float4*)(outI + off) = make_float4(r[0], r[1], r[2], r[3]);
    }
}

extern "C" void kernel_launch(void* const* d_in, const int* in_sizes, int n_in,
                              void* d_out, int out_size, void* d_ws, size_t ws_size,
                              hipStream_t stream)
{
    const float* img = (const float*)d_in[0];
    const float* weight = (const float*)d_in[1];
    float* out = (float*)d_out;
    float* sc = (float*)d_ws;
    float* pd = (float*)((char*)d_ws + 4096);
    float* pn = (float*)((char*)d_ws + 16384);
    __half* imgh = (__half*)((char*)d_ws + 32768);
    uint32_t* ptA = (uint32_t*)((char*)d_ws + 12615680);
    uint32_t* ptB = (uint32_t*)((char*)d_ws + 37781504);

    dim3 grid(8, 8, NIMG);
    dim3 block(256);

    tv_step0<<<grid, block, 0, stream>>>(img, weight, imgh, ptA, pn);

    // it=9's pt output is dead (reference's final out = img + div(pt_8)), so
    // only iterations 1..8 are materialized; tv_out replays it=8's convergence.
    for (int it = 1; it <= 8; ++it) {
        uint32_t* pin  = (((it - 1) & 1) == 0) ? ptA : ptB;
        uint32_t* pout = ((it & 1) == 0) ? ptA : ptB;
        tv_stepN<<<grid, block, 0, stream>>>(it, imgh, weight, pin, pout, sc, pd, pn);
    }
    tv_out<<<grid, block, 0, stream>>>(img, out, ptA, ptB, weight, sc, pd, pn);
}